// Round 9
// baseline (1716.901 us; speedup 1.0000x reference)
//
#include <hip/hip_runtime.h>
#include <math.h>
#include <limits.h>

#define V 100000
#define H 1280
#define E 300
#define L 32
#define NBLK 1563           // ceil(V/64) screen groups (64 rows each)

// ---- workspace layout (4B slots) ----
#define WS_H0     0                    // h buffer, parity 0 steps
#define WS_H1     1280                 // h buffer, parity 1 steps (init: hidden0)
#define WS_EMB    2560                 // emb[300] (fp32-fallback path only)
#define WS_SUMA   2880                 // sum|h| set A (even k): 8 slots, 16-float spacing
#define WS_SUMB   3008                 // sum|h| set B (odd k)
#define WS_DONE0  3136                 // int: done_out(t) for even t
#define WS_DONE1  3137                 // int: done_out(t) for odd t
#define WS_LOGITS 3140                 // float[100000]
#define WS_SROW   (WS_LOGITS + V)      // float[100000] int8 row scales
#define WS_PLO    (WS_SROW + V)        // float[NBLK]
#define WS_PHI    (WS_PLO + NBLK)      // float[NBLK]
#define WS_Q_BYTEOFF 825088            // 16B-aligned, past all of the above
#define WS_BYTES_NEEDED (WS_Q_BYTEOFF + (size_t)V * H)
#define CAND_CAP 256
#define PBLK_CAP 128

// ---- fp32 fallback layout (exclusive path, tiny-ws only) ----
#define FB_GI     4000
#define FB_GH     (FB_GI + 3840)
#define FB_NPART  6250
#define FB_PVAL   12000
#define FB_PIDX   (FB_PVAL + FB_NPART)

__global__ __launch_bounds__(256)
void init_state(const float* __restrict__ hidden0, const float* __restrict__ start_emb,
                float* __restrict__ ws) {
    int i = blockIdx.x * blockDim.x + threadIdx.x;
    if (i < H) { ws[WS_H0 + i] = hidden0[i]; ws[WS_H1 + i] = hidden0[i]; }
    if (i < E) ws[WS_EMB + i] = start_emb[i];
    if (i < 8) { ws[WS_SUMA + i * 16] = 0.f; ws[WS_SUMB + i * 16] = 0.f; }
    if (i == 0) { ((int*)ws)[WS_DONE0] = 0; ((int*)ws)[WS_DONE1] = 0; }
}

// Per-row int8 quantization of W_cls: one wave per row (proven R2-R8).
__global__ __launch_bounds__(256)
void convert_int8(const float* __restrict__ W, uint* __restrict__ q_out,
                  float* __restrict__ ws) {
    const int wave = threadIdx.x >> 6;
    const int lane = threadIdx.x & 63;
    const int row = blockIdx.x * 4 + wave;
    const float4* __restrict__ wr = (const float4*)(W + (size_t)row * H);

    float4 v[5];
    float mx = 0.f;
    #pragma unroll
    for (int k = 0; k < 5; ++k) {
        v[k] = wr[lane + 64*k];
        mx = fmaxf(mx, fmaxf(fmaxf(fabsf(v[k].x), fabsf(v[k].y)),
                             fmaxf(fabsf(v[k].z), fabsf(v[k].w))));
    }
    #pragma unroll
    for (int off = 32; off; off >>= 1) mx = fmaxf(mx, __shfl_xor(mx, off));

    float inv = (mx > 0.f) ? 127.0f / mx : 0.f;
    float s   = (mx > 0.f) ? mx / 127.0f : 0.f;

    uint* __restrict__ qrow = q_out + (size_t)row * (H/4);
    #pragma unroll
    for (int k = 0; k < 5; ++k) {
        int q0 = max(-127, min(127, __float2int_rn(v[k].x * inv)));
        int q1 = max(-127, min(127, __float2int_rn(v[k].y * inv)));
        int q2 = max(-127, min(127, __float2int_rn(v[k].z * inv)));
        int q3 = max(-127, min(127, __float2int_rn(v[k].w * inv)));
        qrow[lane + 64*k] = (uint)(q0 & 0xff) | ((uint)(q1 & 0xff) << 8) |
                            ((uint)(q2 & 0xff) << 16) | ((uint)(q3 & 0xff) << 24);
    }
    if (lane == 0) ws[WS_SROW + row] = s;
}

// Fused kernel per step k, grid = 1280 blocks x 256 thr (block = hidden unit).
//  (a) k>0: REDUNDANT finalize of token[k-1] in every block (deterministic,
//      no cross-block comm); block 0 writes out[k-1]; done ping-pong slots.
//  (b) emb_k -> LDS; GRU: waves 0-2 = gates r,z,n of unit j = blockIdx.x;
//      combine via LDS; h_k, hiddens[k], sum|h_k| into set(k&1).
__global__ __launch_bounds__(256)
void fin_gru(const float* __restrict__ W_ih, const float* __restrict__ W_hh,
             const float* __restrict__ b_ih, const float* __restrict__ b_hh,
             const float* __restrict__ W_cls, const float* __restrict__ b_cls,
             const float* __restrict__ vocab, const float* __restrict__ start_emb,
             float* __restrict__ ws, float* __restrict__ out,
             float* __restrict__ hid_out, int k) {
    __shared__ float red[256];
    __shared__ int   npass, cnt;
    __shared__ int   pblk[PBLK_CAP];
    __shared__ int   cidx[CAND_CAP];
    __shared__ float cval[CAND_CAP];
    __shared__ int   s_pred, s_done;
    __shared__ float gi_s[3], gh_s[3];
    __shared__ __align__(16) float emb_s[304];

    const int tid  = threadIdx.x;
    const int wave = tid >> 6;
    const int lane = tid & 63;

    const float* hin  = ws + ((k & 1) ^ 1) * H;   // h_{k-1}
    float*       hout = ws + (k & 1) * H;         // h_k

    if (k == 0) {
        for (int i = tid; i < E; i += 256) emb_s[i] = start_emb[i];
        if (tid == 0) s_done = 0;
        __syncthreads();
    } else {
        // sum|h_{k-1}| from set ((k-1)&1)
        const int sslot = ((k - 1) & 1) ? WS_SUMB : WS_SUMA;
        float sumabs = 0.f;
        #pragma unroll
        for (int i = 0; i < 8; ++i) sumabs += ws[sslot + i * 16];

        // m = max(PLO)
        float m = -INFINITY;
        for (int b = tid; b < NBLK; b += 256) m = fmaxf(m, ws[WS_PLO + b]);
        red[tid] = m;
        __syncthreads();
        for (int s = 128; s; s >>= 1) {
            if (tid < s) red[tid] = fmaxf(red[tid], red[tid + s]);
            __syncthreads();
        }
        m = red[0];
        if (tid == 0) { npass = 0; cnt = 0; }
        __syncthreads();

        for (int b = tid; b < NBLK; b += 256) {
            if (ws[WS_PHI + b] >= m) {
                int p = atomicAdd(&npass, 1);
                if (p < PBLK_CAP) pblk[p] = b;
            }
        }
        __syncthreads();
        const int np = min(npass, PBLK_CAP);

        for (int j = tid; j < np * 64; j += 256) {
            int row = pblk[j >> 6] * 64 + (j & 63);
            if (row < V) {
                float s = ws[WS_SROW + row];
                float e = 0.501f * s * sumabs + 0.002f;
                if (ws[WS_LOGITS + row] + e >= m) {
                    int p = atomicAdd(&cnt, 1);
                    if (p < CAND_CAP) cidx[p] = row;
                }
            }
        }
        __syncthreads();
        const int nc = min(cnt, CAND_CAP);

        // exact fp32 rescore on h_{k-1} (wave per candidate; L2-hot across blocks)
        const float4* h4r = (const float4*)hin;
        for (int c = wave; c < nc; c += 4) {
            int row = cidx[c];
            const float4* wr = (const float4*)(W_cls + (size_t)row * H);
            float s = 0.f;
            #pragma unroll
            for (int kk = 0; kk < 5; ++kk) {
                float4 wv = wr[lane + 64*kk], hv = h4r[lane + 64*kk];
                s += wv.x*hv.x + wv.y*hv.y + wv.z*hv.z + wv.w*hv.w;
            }
            #pragma unroll
            for (int off = 32; off; off >>= 1) s += __shfl_down(s, off);
            if (lane == 0) cval[c] = s + b_cls[row];
        }
        __syncthreads();

        if (tid == 0) {
            float bv = -INFINITY; int bi = INT_MAX;
            for (int c = 0; c < nc; ++c) {
                float v = cval[c]; int i = cidx[c];
                if (v > bv || (v == bv && i < bi)) { bv = v; bi = i; }
            }
            int pred = bi;
            // done_in(k-1) = done_out(k-2), stored at slot ((k-2)&1) == (k&1)
            int done_in = (k >= 2) ? ((const int*)ws)[(k & 1) ? WS_DONE1 : WS_DONE0] : 0;
            if (blockIdx.x == 0) out[k - 1] = (float)(done_in ? 0 : pred);
            int dn = done_in | (pred == 0);
            ((int*)ws)[((k - 1) & 1) ? WS_DONE1 : WS_DONE0] = dn;  // same value, all blocks
            s_pred = pred; s_done = dn;                             // done_in(k)
        }
        __syncthreads();
        const int pr = s_pred;
        for (int i = tid; i < E; i += 256) emb_s[i] = vocab[(size_t)pr * E + i];
        __syncthreads();
    }

    // ---- GRU: block = unit j, waves 0-2 = gates (R5-proven geometry) ----
    const int j = blockIdx.x;
    if (wave < 3) {
        const int row = wave * H + j;
        const float4* emb4 = (const float4*)emb_s;
        const float4* h4   = (const float4*)hin;

        const float4* wi = (const float4*)(W_ih + (size_t)row * E);
        float si = 0.f;
        for (int i = lane; i < 75; i += 64) {
            float4 w = wi[i], e = emb4[i];
            si += w.x*e.x + w.y*e.y + w.z*e.z + w.w*e.w;
        }
        const float4* wh = (const float4*)(W_hh + (size_t)row * H);
        float sh = 0.f;
        #pragma unroll
        for (int kk = 0; kk < 5; ++kk) {
            float4 w = wh[lane + 64*kk], hv = h4[lane + 64*kk];
            sh += w.x*hv.x + w.y*hv.y + w.z*hv.z + w.w*hv.w;
        }
        #pragma unroll
        for (int off = 32; off; off >>= 1) {
            si += __shfl_down(si, off);
            sh += __shfl_down(sh, off);
        }
        if (lane == 0) {
            gi_s[wave] = si + b_ih[row];
            gh_s[wave] = sh + b_hh[row];
        }
    }
    __syncthreads();
    if (tid == 0) {
        float r = 1.f / (1.f + expf(-(gi_s[0] + gh_s[0])));
        float z = 1.f / (1.f + expf(-(gi_s[1] + gh_s[1])));
        float n = tanhf(gi_s[2] + r * gh_s[2]);
        float hold = hin[j];
        float hnew = s_done ? hold : (1.f - z) * n + z * hold;
        hout[j] = hnew;
        hid_out[j] = hnew;
        const int aslot = (k & 1) ? WS_SUMB : WS_SUMA;
        atomicAdd(ws + aslot + (j & 7) * 16, fabsf(hnew));
    }
}

// int8 classifier screen for step k: 64 rows/block. Reads h_k and sum set (k&1);
// block 0 also resets sum set ((k+1)&1) for the next step's accumulation.
__global__ __launch_bounds__(256)
void cls_int8(const uint* __restrict__ Q, const float* __restrict__ b_cls,
              float* __restrict__ ws, const float* __restrict__ h, int k) {
    if (blockIdx.x == 0 && threadIdx.x < 8)
        ws[(((k + 1) & 1) ? WS_SUMB : WS_SUMA) + threadIdx.x * 16] = 0.f;

    const int wave = threadIdx.x >> 6;
    const int lane = threadIdx.x & 63;
    const int row0 = blockIdx.x * 64 + wave * 16;
    const float4* __restrict__ h4 = (const float4*)h;

    float4 hv[5];
    #pragma unroll
    for (int kk = 0; kk < 5; ++kk) hv[kk] = h4[lane + 64*kk];

    const int sslot = (k & 1) ? WS_SUMB : WS_SUMA;
    float sumabs = 0.f;
    #pragma unroll
    for (int i = 0; i < 8; ++i) sumabs += ws[sslot + i * 16];

    float wlo = -INFINITY, whi = -INFINITY;
    for (int rr = 0; rr < 16; ++rr) {
        const int row = row0 + rr;
        if (row >= V) break;                  // wave-uniform
        const uint* __restrict__ qr = Q + (size_t)row * (H/4);
        float acc = 0.f;
        #pragma unroll
        for (int kk = 0; kk < 5; ++kk) {
            uint u = qr[lane + 64*kk];
            float f0 = (float)((int)(u << 24) >> 24);
            float f1 = (float)((int)(u << 16) >> 24);
            float f2 = (float)((int)(u <<  8) >> 24);
            float f3 = (float)((int) u        >> 24);
            acc += f0*hv[kk].x + f1*hv[kk].y + f2*hv[kk].z + f3*hv[kk].w;
        }
        #pragma unroll
        for (int off = 32; off; off >>= 1) acc += __shfl_down(acc, off);
        if (lane == 0) {
            float s = ws[WS_SROW + row];
            float q = s * acc + b_cls[row];
            ws[WS_LOGITS + row] = q;
            float e = 0.501f * s * sumabs + 0.002f;
            wlo = fmaxf(wlo, q - e);
            whi = fmaxf(whi, q + e);
        }
    }
    __shared__ float slo[4], shi[4];
    if (lane == 0) { slo[wave] = wlo; shi[wave] = whi; }
    __syncthreads();
    if (threadIdx.x == 0) {
        ws[WS_PLO + blockIdx.x] = fmaxf(fmaxf(slo[0], slo[1]), fmaxf(slo[2], slo[3]));
        ws[WS_PHI + blockIdx.x] = fmaxf(fmaxf(shi[0], shi[1]), fmaxf(shi[2], shi[3]));
    }
}

// Tail: token[L-1] from cls(L-1) partials. h_31 in WS_H1 (31 odd), sum set B.
__global__ __launch_bounds__(256)
void finalize_tail(float* __restrict__ ws, const float* __restrict__ W_cls,
                   const float* __restrict__ b_cls, float* __restrict__ out) {
    __shared__ float red[256];
    __shared__ int   npass, cnt;
    __shared__ int   pblk[PBLK_CAP];
    __shared__ int   cidx[CAND_CAP];
    __shared__ float cval[CAND_CAP];
    const int tid = threadIdx.x;
    const int wave = tid >> 6, lane = tid & 63;

    float sumabs = 0.f;
    #pragma unroll
    for (int i = 0; i < 8; ++i) sumabs += ws[WS_SUMB + i * 16];

    float m = -INFINITY;
    for (int b = tid; b < NBLK; b += 256) m = fmaxf(m, ws[WS_PLO + b]);
    red[tid] = m;
    __syncthreads();
    for (int s = 128; s; s >>= 1) {
        if (tid < s) red[tid] = fmaxf(red[tid], red[tid + s]);
        __syncthreads();
    }
    m = red[0];
    if (tid == 0) { npass = 0; cnt = 0; }
    __syncthreads();

    for (int b = tid; b < NBLK; b += 256) {
        if (ws[WS_PHI + b] >= m) {
            int p = atomicAdd(&npass, 1);
            if (p < PBLK_CAP) pblk[p] = b;
        }
    }
    __syncthreads();
    const int np = min(npass, PBLK_CAP);

    for (int j = tid; j < np * 64; j += 256) {
        int row = pblk[j >> 6] * 64 + (j & 63);
        if (row < V) {
            float s = ws[WS_SROW + row];
            float e = 0.501f * s * sumabs + 0.002f;
            if (ws[WS_LOGITS + row] + e >= m) {
                int p = atomicAdd(&cnt, 1);
                if (p < CAND_CAP) cidx[p] = row;
            }
        }
    }
    __syncthreads();
    const int nc = min(cnt, CAND_CAP);

    const float4* h4 = (const float4*)(ws + WS_H1);
    for (int c = wave; c < nc; c += 4) {
        int row = cidx[c];
        const float4* wr = (const float4*)(W_cls + (size_t)row * H);
        float s = 0.f;
        #pragma unroll
        for (int kk = 0; kk < 5; ++kk) {
            float4 wv = wr[lane + 64*kk], hv = h4[lane + 64*kk];
            s += wv.x*hv.x + wv.y*hv.y + wv.z*hv.z + wv.w*hv.w;
        }
        #pragma unroll
        for (int off = 32; off; off >>= 1) s += __shfl_down(s, off);
        if (lane == 0) cval[c] = s + b_cls[row];
    }
    __syncthreads();

    if (tid == 0) {
        float bv = -INFINITY; int bi = INT_MAX;
        for (int c = 0; c < nc; ++c) {
            float v = cval[c]; int i = cidx[c];
            if (v > bv || (v == bv && i < bi)) { bv = v; bi = i; }
        }
        int done_in = ((const int*)ws)[WS_DONE0];   // done_out(30), slot 0
        out[L - 1] = (float)(done_in ? 0 : bi);
    }
}

// ---------- fp32 fallback path (tiny-ws only, R0-proven) ----------
__global__ __launch_bounds__(256)
void fb_gru_matvec(const float* __restrict__ W_ih, const float* __restrict__ W_hh,
                   const float* __restrict__ b_ih, const float* __restrict__ b_hh,
                   float* __restrict__ ws) {
    const int wave = threadIdx.x >> 6;
    const int lane = threadIdx.x & 63;
    const int row = blockIdx.x * 4 + wave;
    const float4* __restrict__ emb4 = (const float4*)(ws + WS_EMB);
    const float4* __restrict__ h4   = (const float4*)(ws + WS_H0);
    const float4* __restrict__ wi = (const float4*)(W_ih + (size_t)row * E);
    float s1 = 0.f;
    for (int i = lane; i < 75; i += 64) {
        float4 w = wi[i], e = emb4[i];
        s1 += w.x*e.x + w.y*e.y + w.z*e.z + w.w*e.w;
    }
    const float4* __restrict__ wh = (const float4*)(W_hh + (size_t)row * H);
    float s2 = 0.f;
    #pragma unroll
    for (int k = 0; k < 5; ++k) {
        float4 w = wh[lane + 64*k], hv = h4[lane + 64*k];
        s2 += w.x*hv.x + w.y*hv.y + w.z*hv.z + w.w*hv.w;
    }
    #pragma unroll
    for (int off = 32; off; off >>= 1) {
        s1 += __shfl_down(s1, off);
        s2 += __shfl_down(s2, off);
    }
    if (lane == 0) {
        ws[FB_GI + row] = s1 + b_ih[row];
        ws[FB_GH + row] = s2 + b_hh[row];
    }
}

__global__ __launch_bounds__(256)
void fb_gru_combine(float* __restrict__ ws, float* __restrict__ hid_out) {
    int j = blockIdx.x * 256 + threadIdx.x;
    if (j >= H) return;
    int done = ((const int*)ws)[WS_DONE0];
    float gir = ws[FB_GI + j], giz = ws[FB_GI + H + j], gin = ws[FB_GI + 2*H + j];
    float ghr = ws[FB_GH + j], ghz = ws[FB_GH + H + j], ghn = ws[FB_GH + 2*H + j];
    float r = 1.f / (1.f + expf(-(gir + ghr)));
    float z = 1.f / (1.f + expf(-(giz + ghz)));
    float n = tanhf(gin + r * ghn);
    float hold = ws[WS_H0 + j];
    float hnew = done ? hold : (1.f - z) * n + z * hold;
    ws[WS_H0 + j] = hnew;
    hid_out[j] = hnew;
}

__global__ __launch_bounds__(256)
void fb_logits_argmax(const float* __restrict__ W_cls, const float* __restrict__ b_cls,
                      float* __restrict__ ws) {
    const int wave = threadIdx.x >> 6;
    const int lane = threadIdx.x & 63;
    const int row0 = blockIdx.x * 16 + wave * 4;
    const float4* __restrict__ h4 = (const float4*)(ws + WS_H0);
    float best = -INFINITY;
    int bidx = INT_MAX;
    for (int rr = 0; rr < 4; ++rr) {
        const int row = row0 + rr;
        const float4* __restrict__ wr = (const float4*)(W_cls + (size_t)row * H);
        float s = 0.f;
        #pragma unroll
        for (int k = 0; k < 5; ++k) {
            float4 w = wr[lane + 64*k], hv = h4[lane + 64*k];
            s += w.x*hv.x + w.y*hv.y + w.z*hv.z + w.w*hv.w;
        }
        #pragma unroll
        for (int off = 32; off; off >>= 1) s += __shfl_down(s, off);
        if (lane == 0) {
            float logit = s + b_cls[row];
            if (logit > best) { best = logit; bidx = row; }
        }
    }
    __shared__ float sval[4];
    __shared__ int   sidx[4];
    if (lane == 0) { sval[wave] = best; sidx[wave] = bidx; }
    __syncthreads();
    if (threadIdx.x == 0) {
        float bv = sval[0]; int bi = sidx[0];
        #pragma unroll
        for (int w = 1; w < 4; ++w)
            if (sval[w] > bv || (sval[w] == bv && sidx[w] < bi)) { bv = sval[w]; bi = sidx[w]; }
        ws[FB_PVAL + blockIdx.x] = bv;
        ((int*)ws)[FB_PIDX + blockIdx.x] = bi;
    }
}

__global__ __launch_bounds__(1024)
void fb_argmax_update(float* __restrict__ ws, const float* __restrict__ vocab,
                      float* __restrict__ tok_out, int t) {
    __shared__ float sval[1024];
    __shared__ int   sidx[1024];
    const int tid = threadIdx.x;
    float best = -INFINITY;
    int bidx = INT_MAX;
    for (int i = tid; i < FB_NPART; i += 1024) {
        float v = ws[FB_PVAL + i];
        int  id = ((const int*)ws)[FB_PIDX + i];
        if (v > best || (v == best && id < bidx)) { best = v; bidx = id; }
    }
    sval[tid] = best; sidx[tid] = bidx;
    __syncthreads();
    #pragma unroll
    for (int s = 512; s; s >>= 1) {
        if (tid < s) {
            if (sval[tid+s] > sval[tid] ||
                (sval[tid+s] == sval[tid] && sidx[tid+s] < sidx[tid])) {
                sval[tid] = sval[tid+s]; sidx[tid] = sidx[tid+s];
            }
        }
        __syncthreads();
    }
    __shared__ int s_pred, s_donenew;
    if (tid == 0) {
        int pred = sidx[0];
        int done = ((const int*)ws)[WS_DONE0];
        tok_out[t] = (float)(done ? 0 : pred);
        int done_new = done | (pred == 0);
        ((int*)ws)[WS_DONE0] = done_new;
        s_pred = pred; s_donenew = done_new;
    }
    __syncthreads();
    if (!s_donenew && tid < E)
        ws[WS_EMB + tid] = vocab[(size_t)s_pred * E + tid];
}

extern "C" void kernel_launch(void* const* d_in, const int* in_sizes, int n_in,
                              void* d_out, int out_size, void* d_ws, size_t ws_size,
                              hipStream_t stream) {
    const float* hidden0   = (const float*)d_in[0];
    const float* start_emb = (const float*)d_in[1];
    const float* W_ih      = (const float*)d_in[2];
    const float* W_hh      = (const float*)d_in[3];
    const float* b_ih      = (const float*)d_in[4];
    const float* b_hh      = (const float*)d_in[5];
    const float* W_cls     = (const float*)d_in[6];
    const float* b_cls     = (const float*)d_in[7];
    const float* vocab     = (const float*)d_in[8];
    float* out = (float*)d_out;
    float* ws  = (float*)d_ws;

    hipLaunchKernelGGL(init_state, dim3(5), dim3(256), 0, stream, hidden0, start_emb, ws);

    if (ws_size >= WS_BYTES_NEEDED) {
        uint* Q = (uint*)((char*)d_ws + WS_Q_BYTEOFF);
        hipLaunchKernelGGL(convert_int8, dim3(V/4), dim3(256), 0, stream, W_cls, Q, ws);
        for (int k = 0; k < L; ++k) {
            const float* hk = ws + (k & 1) * H;   // h_k (written by fin_gru)
            hipLaunchKernelGGL(fin_gru, dim3(H), dim3(256), 0, stream,
                               W_ih, W_hh, b_ih, b_hh, W_cls, b_cls, vocab,
                               start_emb, ws, out, out + L + (size_t)k * H, k);
            hipLaunchKernelGGL(cls_int8, dim3(NBLK), dim3(256), 0, stream,
                               Q, b_cls, ws, hk, k);
        }
        hipLaunchKernelGGL(finalize_tail, dim3(1), dim3(256), 0, stream,
                           ws, W_cls, b_cls, out);
    } else {
        for (int t = 0; t < L; ++t) {
            hipLaunchKernelGGL(fb_gru_matvec, dim3(960), dim3(256), 0, stream,
                               W_ih, W_hh, b_ih, b_hh, ws);
            hipLaunchKernelGGL(fb_gru_combine, dim3(5), dim3(256), 0, stream,
                               ws, out + L + (size_t)t * H);
            hipLaunchKernelGGL(fb_logits_argmax, dim3(FB_NPART), dim3(256), 0, stream,
                               W_cls, b_cls, ws);
            hipLaunchKernelGGL(fb_argmax_update, dim3(1), dim3(1024), 0, stream,
                               ws, vocab, out, t);
        }
    }
}

// Round 10
// 1573.491 us; speedup vs baseline: 1.0911x; 1.0911x over previous
//
#include <hip/hip_runtime.h>
#include <math.h>
#include <limits.h>

#define V 100000
#define H 1280
#define E 300
#define L 32
#define NBLK 1563           // ceil(V/64) screen groups (64 rows each)
#define GHBLK 320           // extra blocks for W_hh GEMV (320*4 waves*3 rows = 3840)

// ---- main-path workspace layout (4B slots) ----
#define WS_H0     0                    // h ping
#define WS_H1     1280                 // h pong
#define WS_EMB    2560                 // emb[300] (pad 320)
#define WS_SUM8   2880                 // 8 partial sum|h| slots, 16-float spacing
#define WS_DONE   3008                 // int done flag
#define WS_GH     3072                 // gh[3840] = W_hh@h + b_hh (for NEXT gru)
#define WS_LOGITS 6912                 // float[100000]
#define WS_SROW   (WS_LOGITS + V)      // float[100000]
#define WS_PLO    (WS_SROW + V)        // float[NBLK]
#define WS_PHI    (WS_PLO + NBLK)      // float[NBLK]
#define WS_Q_BYTEOFF 840192            // 16B-aligned, past 210038*4=840152
#define WS_BYTES_NEEDED (WS_Q_BYTEOFF + (size_t)V * H)
#define CAND_CAP 256
#define PBLK_CAP 128

// ---- fp32 fallback layout (exclusive path, tiny-ws only) ----
#define FB_GI     4000
#define FB_GH     (FB_GI + 3840)
#define FB_NPART  6250
#define FB_PVAL   12000
#define FB_PIDX   (FB_PVAL + FB_NPART)

__global__ __launch_bounds__(256)
void init_state(const float* __restrict__ hidden0, const float* __restrict__ start_emb,
                float* __restrict__ ws) {
    int i = blockIdx.x * blockDim.x + threadIdx.x;
    if (i < H) ws[WS_H0 + i] = hidden0[i];
    if (i < E) ws[WS_EMB + i] = start_emb[i];
    if (i < 8) ws[WS_SUM8 + i * 16] = 0.f;
    if (i == 0) ((int*)ws)[WS_DONE] = 0;
}

// Per-row int8 quantization of W_cls (blocks < V/4), one wave per row.
// Blocks >= V/4: initial gh = W_hh @ h0 + b_hh (h0 in WS_H0, set by init_state).
__global__ __launch_bounds__(256)
void convert_int8(const float* __restrict__ W, uint* __restrict__ q_out,
                  float* __restrict__ ws, const float* __restrict__ W_hh,
                  const float* __restrict__ b_hh) {
    const int wave = threadIdx.x >> 6;
    const int lane = threadIdx.x & 63;

    if (blockIdx.x >= V/4) {
        const int tb = (blockIdx.x - V/4) * 4 + wave;      // [0,1280)
        const float4* h4 = (const float4*)(ws + WS_H0);
        float4 hv[5];
        #pragma unroll
        for (int k = 0; k < 5; ++k) hv[k] = h4[lane + 64*k];
        #pragma unroll
        for (int rr = 0; rr < 3; ++rr) {
            const int row = tb * 3 + rr;
            const float4* wr = (const float4*)(W_hh + (size_t)row * H);
            float s = 0.f;
            #pragma unroll
            for (int k = 0; k < 5; ++k) {
                float4 w = wr[lane + 64*k];
                s += w.x*hv[k].x + w.y*hv[k].y + w.z*hv[k].z + w.w*hv[k].w;
            }
            #pragma unroll
            for (int off = 32; off; off >>= 1) s += __shfl_down(s, off);
            if (lane == 0) ws[WS_GH + row] = s + b_hh[row];
        }
        return;
    }

    const int row = blockIdx.x * 4 + wave;
    const float4* __restrict__ wr = (const float4*)(W + (size_t)row * H);

    float4 v[5];
    float mx = 0.f;
    #pragma unroll
    for (int k = 0; k < 5; ++k) {
        v[k] = wr[lane + 64*k];
        mx = fmaxf(mx, fmaxf(fmaxf(fabsf(v[k].x), fabsf(v[k].y)),
                             fmaxf(fabsf(v[k].z), fabsf(v[k].w))));
    }
    #pragma unroll
    for (int off = 32; off; off >>= 1) mx = fmaxf(mx, __shfl_xor(mx, off));

    float inv = (mx > 0.f) ? 127.0f / mx : 0.f;
    float s   = (mx > 0.f) ? mx / 127.0f : 0.f;

    uint* __restrict__ qrow = q_out + (size_t)row * (H/4);
    #pragma unroll
    for (int k = 0; k < 5; ++k) {
        int q0 = max(-127, min(127, __float2int_rn(v[k].x * inv)));
        int q1 = max(-127, min(127, __float2int_rn(v[k].y * inv)));
        int q2 = max(-127, min(127, __float2int_rn(v[k].z * inv)));
        int q3 = max(-127, min(127, __float2int_rn(v[k].w * inv)));
        qrow[lane + 64*k] = (uint)(q0 & 0xff) | ((uint)(q1 & 0xff) << 8) |
                            ((uint)(q2 & 0xff) << 16) | ((uint)(q3 & 0xff) << 24);
    }
    if (lane == 0) ws[WS_SROW + row] = s;
}

// GRU finish (R5 geometry: block = hidden unit j, 3 waves = 3 gates).
// gh was precomputed by the previous cls (or convert prologue). Only the
// W_ih@emb dot (4.6 MB) remains on the serial critical path.
__global__ __launch_bounds__(192)
void gru_fused(const float* __restrict__ W_ih, const float* __restrict__ b_ih,
               float* __restrict__ ws, const float* __restrict__ hin,
               float* __restrict__ hout, float* __restrict__ hid_out) {
    const int g = threadIdx.x >> 6;      // gate 0=r,1=z,2=n
    const int lane = threadIdx.x & 63;
    const int j = blockIdx.x;
    const int row = g * H + j;

    const float4* __restrict__ emb4 = (const float4*)(ws + WS_EMB);
    const float4* __restrict__ wi = (const float4*)(W_ih + (size_t)row * E);
    float si = 0.f;
    for (int i = lane; i < 75; i += 64) {
        float4 w = wi[i], e = emb4[i];
        si += w.x*e.x + w.y*e.y + w.z*e.z + w.w*e.w;
    }
    #pragma unroll
    for (int off = 32; off; off >>= 1) si += __shfl_down(si, off);

    __shared__ float gi_s[3];
    if (lane == 0) gi_s[g] = si + b_ih[row];
    __syncthreads();
    if (threadIdx.x == 0) {
        float r = 1.f / (1.f + expf(-(gi_s[0] + ws[WS_GH + j])));
        float z = 1.f / (1.f + expf(-(gi_s[1] + ws[WS_GH + H + j])));
        float n = tanhf(gi_s[2] + r * ws[WS_GH + 2*H + j]);
        int done = ((const int*)ws)[WS_DONE];
        float hold = hin[j];
        float hnew = done ? hold : (1.f - z) * n + z * hold;
        hout[j] = hnew;
        hid_out[j] = hnew;
        atomicAdd(ws + WS_SUM8 + (j & 7) * 16, fabsf(hnew));
    }
}

// int8 classifier screen (blocks < NBLK, 64 rows each) + W_hh GEMV for the
// NEXT step's gru (blocks >= NBLK, unless last step). No global atomics.
__global__ __launch_bounds__(256)
void cls_int8(const uint* __restrict__ Q, const float* __restrict__ b_cls,
              float* __restrict__ ws, const float* __restrict__ h,
              const float* __restrict__ W_hh, const float* __restrict__ b_hh,
              int last) {
    const int wave = threadIdx.x >> 6;
    const int lane = threadIdx.x & 63;

    if (blockIdx.x >= NBLK) {
        if (last) return;
        const int tb = (blockIdx.x - NBLK) * 4 + wave;     // [0,1280)
        const float4* h4 = (const float4*)h;
        float4 hv[5];
        #pragma unroll
        for (int k = 0; k < 5; ++k) hv[k] = h4[lane + 64*k];
        #pragma unroll
        for (int rr = 0; rr < 3; ++rr) {
            const int row = tb * 3 + rr;
            const float4* wr = (const float4*)(W_hh + (size_t)row * H);
            float s = 0.f;
            #pragma unroll
            for (int k = 0; k < 5; ++k) {
                float4 w = wr[lane + 64*k];
                s += w.x*hv[k].x + w.y*hv[k].y + w.z*hv[k].z + w.w*hv[k].w;
            }
            #pragma unroll
            for (int off = 32; off; off >>= 1) s += __shfl_down(s, off);
            if (lane == 0) ws[WS_GH + row] = s + b_hh[row];
        }
        return;
    }

    const int row0 = blockIdx.x * 64 + wave * 16;
    const float4* __restrict__ h4 = (const float4*)h;

    float4 hv[5];
    #pragma unroll
    for (int kk = 0; kk < 5; ++kk) hv[kk] = h4[lane + 64*kk];

    float sumabs = 0.f;
    #pragma unroll
    for (int i = 0; i < 8; ++i) sumabs += ws[WS_SUM8 + i * 16];

    float wlo = -INFINITY, whi = -INFINITY;
    for (int rr = 0; rr < 16; ++rr) {
        const int row = row0 + rr;
        if (row >= V) break;                  // wave-uniform
        const uint* __restrict__ qr = Q + (size_t)row * (H/4);
        float acc = 0.f;
        #pragma unroll
        for (int kk = 0; kk < 5; ++kk) {
            uint u = qr[lane + 64*kk];
            float f0 = (float)((int)(u << 24) >> 24);
            float f1 = (float)((int)(u << 16) >> 24);
            float f2 = (float)((int)(u <<  8) >> 24);
            float f3 = (float)((int) u        >> 24);
            acc += f0*hv[kk].x + f1*hv[kk].y + f2*hv[kk].z + f3*hv[kk].w;
        }
        #pragma unroll
        for (int off = 32; off; off >>= 1) acc += __shfl_down(acc, off);
        if (lane == 0) {
            float s = ws[WS_SROW + row];
            float q = s * acc + b_cls[row];
            ws[WS_LOGITS + row] = q;
            float e = 0.501f * s * sumabs + 0.002f;
            wlo = fmaxf(wlo, q - e);
            whi = fmaxf(whi, q + e);
        }
    }
    __shared__ float slo[4], shi[4];
    if (lane == 0) { slo[wave] = wlo; shi[wave] = whi; }
    __syncthreads();
    if (threadIdx.x == 0) {
        ws[WS_PLO + blockIdx.x] = fmaxf(fmaxf(slo[0], slo[1]), fmaxf(slo[2], slo[3]));
        ws[WS_PHI + blockIdx.x] = fmaxf(fmaxf(shi[0], shi[1]), fmaxf(shi[2], shi[3]));
    }
}

// Single block: m = max(PLO); blocks with PHI >= m -> row candidates;
// exact fp32 rescore; argmax (min-index ties); token/done/emb; reset sum8.
__global__ __launch_bounds__(1024)
void finalize(float* __restrict__ ws, const float* __restrict__ W_cls,
              const float* __restrict__ b_cls, const float* __restrict__ vocab,
              float* __restrict__ tok_out, int t, const float* __restrict__ h) {
    __shared__ float red[1024];
    __shared__ int   npass, cnt;
    __shared__ int   pblk[PBLK_CAP];
    __shared__ int   cidx[CAND_CAP];
    __shared__ float cval[CAND_CAP];
    __shared__ int   s_pred, s_done_new;
    const int tid = threadIdx.x;

    float sumabs = 0.f;
    #pragma unroll
    for (int i = 0; i < 8; ++i) sumabs += ws[WS_SUM8 + i * 16];

    float m = -INFINITY;
    for (int b = tid; b < NBLK; b += 1024) m = fmaxf(m, ws[WS_PLO + b]);
    red[tid] = m;
    __syncthreads();
    for (int s = 512; s; s >>= 1) {
        if (tid < s) red[tid] = fmaxf(red[tid], red[tid + s]);
        __syncthreads();
    }
    m = red[0];
    if (tid == 0) { npass = 0; cnt = 0; }
    __syncthreads();

    for (int b = tid; b < NBLK; b += 1024) {
        if (ws[WS_PHI + b] >= m) {
            int p = atomicAdd(&npass, 1);
            if (p < PBLK_CAP) pblk[p] = b;
        }
    }
    __syncthreads();
    const int np = min(npass, PBLK_CAP);

    for (int k = tid; k < np * 64; k += 1024) {
        int row = pblk[k >> 6] * 64 + (k & 63);
        if (row < V) {
            float s = ws[WS_SROW + row];
            float e = 0.501f * s * sumabs + 0.002f;
            if (ws[WS_LOGITS + row] + e >= m) {
                int p = atomicAdd(&cnt, 1);
                if (p < CAND_CAP) cidx[p] = row;
            }
        }
    }
    __syncthreads();
    const int nc = min(cnt, CAND_CAP);

    const int wave = tid >> 6;
    const int lane = tid & 63;
    const float4* __restrict__ h4 = (const float4*)h;
    for (int c = wave; c < nc; c += 16) {
        int row = cidx[c];
        const float4* __restrict__ wr = (const float4*)(W_cls + (size_t)row * H);
        float s = 0.f;
        #pragma unroll
        for (int k = 0; k < 5; ++k) {
            float4 wv = wr[lane + 64*k], hvv = h4[lane + 64*k];
            s += wv.x*hvv.x + wv.y*hvv.y + wv.z*hvv.z + wv.w*hvv.w;
        }
        #pragma unroll
        for (int off = 32; off; off >>= 1) s += __shfl_down(s, off);
        if (lane == 0) cval[c] = s + b_cls[row];
    }
    __syncthreads();

    if (tid == 0) {
        float bv = -INFINITY; int bi = INT_MAX;
        for (int c = 0; c < nc; ++c) {
            float v = cval[c]; int i = cidx[c];
            if (v > bv || (v == bv && i < bi)) { bv = v; bi = i; }
        }
        int done = ((const int*)ws)[WS_DONE];
        int pred = bi;
        tok_out[t] = (float)(done ? 0 : pred);
        int dn = done | (pred == 0);
        ((int*)ws)[WS_DONE] = dn;
        s_pred = pred; s_done_new = dn;
    }
    __syncthreads();
    if (!s_done_new && tid < E)
        ws[WS_EMB + tid] = vocab[(size_t)s_pred * E + tid];
    if (tid < 8) ws[WS_SUM8 + tid * 16] = 0.f;
}

// ---------- fp32 fallback path (tiny-ws only, R0-proven) ----------
__global__ __launch_bounds__(256)
void fb_gru_matvec(const float* __restrict__ W_ih, const float* __restrict__ W_hh,
                   const float* __restrict__ b_ih, const float* __restrict__ b_hh,
                   float* __restrict__ ws) {
    const int wave = threadIdx.x >> 6;
    const int lane = threadIdx.x & 63;
    const int row = blockIdx.x * 4 + wave;
    const float4* __restrict__ emb4 = (const float4*)(ws + WS_EMB);
    const float4* __restrict__ h4   = (const float4*)(ws + WS_H0);
    const float4* __restrict__ wi = (const float4*)(W_ih + (size_t)row * E);
    float s1 = 0.f;
    for (int i = lane; i < 75; i += 64) {
        float4 w = wi[i], e = emb4[i];
        s1 += w.x*e.x + w.y*e.y + w.z*e.z + w.w*e.w;
    }
    const float4* __restrict__ wh = (const float4*)(W_hh + (size_t)row * H);
    float s2 = 0.f;
    #pragma unroll
    for (int k = 0; k < 5; ++k) {
        float4 w = wh[lane + 64*k], hv = h4[lane + 64*k];
        s2 += w.x*hv.x + w.y*hv.y + w.z*hv.z + w.w*hv.w;
    }
    #pragma unroll
    for (int off = 32; off; off >>= 1) {
        s1 += __shfl_down(s1, off);
        s2 += __shfl_down(s2, off);
    }
    if (lane == 0) {
        ws[FB_GI + row] = s1 + b_ih[row];
        ws[FB_GH + row] = s2 + b_hh[row];
    }
}

__global__ __launch_bounds__(256)
void fb_gru_combine(float* __restrict__ ws, float* __restrict__ hid_out) {
    int j = blockIdx.x * 256 + threadIdx.x;
    if (j >= H) return;
    int done = ((const int*)ws)[WS_DONE];
    float gir = ws[FB_GI + j], giz = ws[FB_GI + H + j], gin = ws[FB_GI + 2*H + j];
    float ghr = ws[FB_GH + j], ghz = ws[FB_GH + H + j], ghn = ws[FB_GH + 2*H + j];
    float r = 1.f / (1.f + expf(-(gir + ghr)));
    float z = 1.f / (1.f + expf(-(giz + ghz)));
    float n = tanhf(gin + r * ghn);
    float hold = ws[WS_H0 + j];
    float hnew = done ? hold : (1.f - z) * n + z * hold;
    ws[WS_H0 + j] = hnew;
    hid_out[j] = hnew;
}

__global__ __launch_bounds__(256)
void fb_logits_argmax(const float* __restrict__ W_cls, const float* __restrict__ b_cls,
                      float* __restrict__ ws) {
    const int wave = threadIdx.x >> 6;
    const int lane = threadIdx.x & 63;
    const int row0 = blockIdx.x * 16 + wave * 4;
    const float4* __restrict__ h4 = (const float4*)(ws + WS_H0);
    float best = -INFINITY;
    int bidx = INT_MAX;
    for (int rr = 0; rr < 4; ++rr) {
        const int row = row0 + rr;
        const float4* __restrict__ wr = (const float4*)(W_cls + (size_t)row * H);
        float s = 0.f;
        #pragma unroll
        for (int k = 0; k < 5; ++k) {
            float4 w = wr[lane + 64*k], hv = h4[lane + 64*k];
            s += w.x*hv.x + w.y*hv.y + w.z*hv.z + w.w*hv.w;
        }
        #pragma unroll
        for (int off = 32; off; off >>= 1) s += __shfl_down(s, off);
        if (lane == 0) {
            float logit = s + b_cls[row];
            if (logit > best) { best = logit; bidx = row; }
        }
    }
    __shared__ float sval[4];
    __shared__ int   sidx[4];
    if (lane == 0) { sval[wave] = best; sidx[wave] = bidx; }
    __syncthreads();
    if (threadIdx.x == 0) {
        float bv = sval[0]; int bi = sidx[0];
        #pragma unroll
        for (int w = 1; w < 4; ++w)
            if (sval[w] > bv || (sval[w] == bv && sidx[w] < bi)) { bv = sval[w]; bi = sidx[w]; }
        ws[FB_PVAL + blockIdx.x] = bv;
        ((int*)ws)[FB_PIDX + blockIdx.x] = bi;
    }
}

__global__ __launch_bounds__(1024)
void fb_argmax_update(float* __restrict__ ws, const float* __restrict__ vocab,
                      float* __restrict__ tok_out, int t) {
    __shared__ float sval[1024];
    __shared__ int   sidx[1024];
    const int tid = threadIdx.x;
    float best = -INFINITY;
    int bidx = INT_MAX;
    for (int i = tid; i < FB_NPART; i += 1024) {
        float v = ws[FB_PVAL + i];
        int  id = ((const int*)ws)[FB_PIDX + i];
        if (v > best || (v == best && id < bidx)) { best = v; bidx = id; }
    }
    sval[tid] = best; sidx[tid] = bidx;
    __syncthreads();
    #pragma unroll
    for (int s = 512; s; s >>= 1) {
        if (tid < s) {
            if (sval[tid+s] > sval[tid] ||
                (sval[tid+s] == sval[tid] && sidx[tid+s] < sidx[tid])) {
                sval[tid] = sval[tid+s]; sidx[tid] = sidx[tid+s];
            }
        }
        __syncthreads();
    }
    __shared__ int s_pred, s_donenew;
    if (tid == 0) {
        int pred = sidx[0];
        int done = ((const int*)ws)[WS_DONE];
        tok_out[t] = (float)(done ? 0 : pred);
        int done_new = done | (pred == 0);
        ((int*)ws)[WS_DONE] = done_new;
        s_pred = pred; s_donenew = done_new;
    }
    __syncthreads();
    if (!s_donenew && tid < E)
        ws[WS_EMB + tid] = vocab[(size_t)s_pred * E + tid];
}

extern "C" void kernel_launch(void* const* d_in, const int* in_sizes, int n_in,
                              void* d_out, int out_size, void* d_ws, size_t ws_size,
                              hipStream_t stream) {
    const float* hidden0   = (const float*)d_in[0];
    const float* start_emb = (const float*)d_in[1];
    const float* W_ih      = (const float*)d_in[2];
    const float* W_hh      = (const float*)d_in[3];
    const float* b_ih      = (const float*)d_in[4];
    const float* b_hh      = (const float*)d_in[5];
    const float* W_cls     = (const float*)d_in[6];
    const float* b_cls     = (const float*)d_in[7];
    const float* vocab     = (const float*)d_in[8];
    float* out = (float*)d_out;
    float* ws  = (float*)d_ws;

    hipLaunchKernelGGL(init_state, dim3(5), dim3(256), 0, stream, hidden0, start_emb, ws);

    if (ws_size >= WS_BYTES_NEEDED) {
        uint* Q = (uint*)((char*)d_ws + WS_Q_BYTEOFF);
        hipLaunchKernelGGL(convert_int8, dim3(V/4 + GHBLK), dim3(256), 0, stream,
                           W_cls, Q, ws, W_hh, b_hh);
        for (int k = 0; k < L; ++k) {
            const float* hin = ws + ((k & 1) ? WS_H1 : WS_H0);
            float* hout      = ws + ((k & 1) ? WS_H0 : WS_H1);
            hipLaunchKernelGGL(gru_fused, dim3(H), dim3(192), 0, stream,
                               W_ih, b_ih, ws, hin, hout, out + L + (size_t)k * H);
            hipLaunchKernelGGL(cls_int8, dim3(NBLK + GHBLK), dim3(256), 0, stream,
                               Q, b_cls, ws, hout, W_hh, b_hh, (k == L - 1) ? 1 : 0);
            hipLaunchKernelGGL(finalize, dim3(1), dim3(1024), 0, stream,
                               ws, W_cls, b_cls, vocab, out, k, hout);
        }
    } else {
        for (int t = 0; t < L; ++t) {
            hipLaunchKernelGGL(fb_gru_matvec, dim3(960), dim3(256), 0, stream,
                               W_ih, W_hh, b_ih, b_hh, ws);
            hipLaunchKernelGGL(fb_gru_combine, dim3(5), dim3(256), 0, stream,
                               ws, out + L + (size_t)t * H);
            hipLaunchKernelGGL(fb_logits_argmax, dim3(FB_NPART), dim3(256), 0, stream,
                               W_cls, b_cls, ws);
            hipLaunchKernelGGL(fb_argmax_update, dim3(1), dim3(1024), 0, stream,
                               ws, vocab, out, t);
        }
    }
}

// Round 12
// 1571.211 us; speedup vs baseline: 1.0927x; 1.0015x over previous
//
#include <hip/hip_runtime.h>
#include <math.h>
#include <limits.h>

#define V 100000
#define H 1280
#define E 300
#define L 32
#define NBLK 1563           // ceil(V/64) screen groups (64 rows each)
#define GHBLK 320           // extra blocks for W_hh GEMV (320*4 waves*3 rows = 3840)

#ifndef __has_builtin
#define __has_builtin(x) 0
#endif
#if __has_builtin(__builtin_amdgcn_sdot4)
__device__ __forceinline__ int dot4i8(uint a, uint b, int c) {
    return __builtin_amdgcn_sdot4((int)a, (int)b, c, false);
}
#else
__device__ __forceinline__ int dot4i8(uint a, uint b, int c) {
    c += ((int)(a << 24) >> 24) * ((int)(b << 24) >> 24);
    c += ((int)(a << 16) >> 24) * ((int)(b << 16) >> 24);
    c += ((int)(a <<  8) >> 24) * ((int)(b <<  8) >> 24);
    c += ((int) a        >> 24) * ((int) b        >> 24);
    return c;
}
#endif

// ---- main-path workspace layout (4B slots) ----
#define WS_H0     0                    // h ping
#define WS_H1     1280                 // h pong
#define WS_EMB    2560                 // emb[300] (pad 320)
#define WS_SUM8   2880                 // 8 partial sum|h| slots, 16-float spacing
#define WS_HMAX8  3008                 // 8 partial max|h| slots (uint-encoded)
#define WS_DONE   3136                 // int done flag
#define WS_GH     3200                 // gh[3840] = W_hh@h + b_hh (for NEXT gru)
#define WS_LOGITS 7040                 // float[100000]
#define WS_SROW   (WS_LOGITS + V)      // float[100000] int8 row scales
#define WS_ASUM   (WS_SROW + V)        // float[100000] per-row sum|q_w|
#define WS_PLO    (WS_ASUM + V)        // float[NBLK]
#define WS_PHI    (WS_PLO + NBLK)      // float[NBLK]
#define WS_Q_BYTEOFF 1240672           // 16B-aligned, past 310166*4=1240664
#define WS_BYTES_NEEDED (WS_Q_BYTEOFF + (size_t)V * H)
#define CAND_CAP 320
#define PBLK_CAP 192
#define INV127 0.007874015748f

// ---- fp32 fallback layout (exclusive path, tiny-ws only) ----
#define FB_GI     4000
#define FB_GH     (FB_GI + 3840)
#define FB_NPART  6250
#define FB_PVAL   12000
#define FB_PIDX   (FB_PVAL + FB_NPART)

__global__ __launch_bounds__(256)
void init_state(const float* __restrict__ hidden0, const float* __restrict__ start_emb,
                float* __restrict__ ws) {
    int i = blockIdx.x * blockDim.x + threadIdx.x;
    if (i < H) ws[WS_H0 + i] = hidden0[i];
    if (i < E) ws[WS_EMB + i] = start_emb[i];
    if (i < 8) { ws[WS_SUM8 + i * 16] = 0.f; ((uint*)ws)[WS_HMAX8 + i * 16] = 0u; }
    if (i == 0) ((int*)ws)[WS_DONE] = 0;
}

// Per-row int8 quantization of W_cls (blocks < V/4): stores s_r and A_r=sum|q|.
// Blocks >= V/4: initial gh = W_hh @ h0 + b_hh.
__global__ __launch_bounds__(256)
void convert_int8(const float* __restrict__ W, uint* __restrict__ q_out,
                  float* __restrict__ ws, const float* __restrict__ W_hh,
                  const float* __restrict__ b_hh) {
    const int wave = threadIdx.x >> 6;
    const int lane = threadIdx.x & 63;

    if (blockIdx.x >= V/4) {
        const int tb = (blockIdx.x - V/4) * 4 + wave;      // [0,1280)
        const float4* h4 = (const float4*)(ws + WS_H0);
        float4 hv[5];
        #pragma unroll
        for (int k = 0; k < 5; ++k) hv[k] = h4[lane + 64*k];
        #pragma unroll
        for (int rr = 0; rr < 3; ++rr) {
            const int row = tb * 3 + rr;
            const float4* wr = (const float4*)(W_hh + (size_t)row * H);
            float s = 0.f;
            #pragma unroll
            for (int k = 0; k < 5; ++k) {
                float4 w = wr[lane + 64*k];
                s += w.x*hv[k].x + w.y*hv[k].y + w.z*hv[k].z + w.w*hv[k].w;
            }
            #pragma unroll
            for (int off = 32; off; off >>= 1) s += __shfl_down(s, off);
            if (lane == 0) ws[WS_GH + row] = s + b_hh[row];
        }
        return;
    }

    const int row = blockIdx.x * 4 + wave;
    const float4* __restrict__ wr = (const float4*)(W + (size_t)row * H);

    float4 v[5];
    float mx = 0.f;
    #pragma unroll
    for (int k = 0; k < 5; ++k) {
        v[k] = wr[lane + 64*k];
        mx = fmaxf(mx, fmaxf(fmaxf(fabsf(v[k].x), fabsf(v[k].y)),
                             fmaxf(fabsf(v[k].z), fabsf(v[k].w))));
    }
    #pragma unroll
    for (int off = 32; off; off >>= 1) mx = fmaxf(mx, __shfl_xor(mx, off));

    float inv = (mx > 0.f) ? 127.0f / mx : 0.f;
    float s   = (mx > 0.f) ? mx / 127.0f : 0.f;

    uint* __restrict__ qrow = q_out + (size_t)row * (H/4);
    int asum = 0;
    #pragma unroll
    for (int k = 0; k < 5; ++k) {
        int q0 = max(-127, min(127, __float2int_rn(v[k].x * inv)));
        int q1 = max(-127, min(127, __float2int_rn(v[k].y * inv)));
        int q2 = max(-127, min(127, __float2int_rn(v[k].z * inv)));
        int q3 = max(-127, min(127, __float2int_rn(v[k].w * inv)));
        asum += abs(q0) + abs(q1) + abs(q2) + abs(q3);
        qrow[lane + 64*k] = (uint)(q0 & 0xff) | ((uint)(q1 & 0xff) << 8) |
                            ((uint)(q2 & 0xff) << 16) | ((uint)(q3 & 0xff) << 24);
    }
    #pragma unroll
    for (int off = 32; off; off >>= 1) asum += __shfl_down(asum, off);
    if (lane == 0) { ws[WS_SROW + row] = s; ws[WS_ASUM + row] = (float)asum; }
}

// GRU finish (block = hidden unit j, 3 waves = 3 gates). gh precomputed.
__global__ __launch_bounds__(192)
void gru_fused(const float* __restrict__ W_ih, const float* __restrict__ b_ih,
               float* __restrict__ ws, const float* __restrict__ hin,
               float* __restrict__ hout, float* __restrict__ hid_out) {
    const int g = threadIdx.x >> 6;      // gate 0=r,1=z,2=n
    const int lane = threadIdx.x & 63;
    const int j = blockIdx.x;
    const int row = g * H + j;

    const float4* __restrict__ emb4 = (const float4*)(ws + WS_EMB);
    const float4* __restrict__ wi = (const float4*)(W_ih + (size_t)row * E);
    float si = 0.f;
    for (int i = lane; i < 75; i += 64) {
        float4 w = wi[i], e = emb4[i];
        si += w.x*e.x + w.y*e.y + w.z*e.z + w.w*e.w;
    }
    #pragma unroll
    for (int off = 32; off; off >>= 1) si += __shfl_down(si, off);

    __shared__ float gi_s[3];
    if (lane == 0) gi_s[g] = si + b_ih[row];
    __syncthreads();
    if (threadIdx.x == 0) {
        float r = 1.f / (1.f + expf(-(gi_s[0] + ws[WS_GH + j])));
        float z = 1.f / (1.f + expf(-(gi_s[1] + ws[WS_GH + H + j])));
        float n = tanhf(gi_s[2] + r * ws[WS_GH + 2*H + j]);
        int done = ((const int*)ws)[WS_DONE];
        float hold = hin[j];
        float hnew = done ? hold : (1.f - z) * n + z * hold;
        hout[j] = hnew;
        hid_out[j] = hnew;
        float a = fabsf(hnew);
        atomicAdd(ws + WS_SUM8 + (j & 7) * 16, a);
        atomicMax((uint*)ws + WS_HMAX8 + (j & 7) * 16, __float_as_uint(a));
    }
}

// int8 x residual-int8 classifier screen via dot4 (blocks < NBLK, 64 rows) +
// W_hh GEMV for next step (blocks >= NBLK, unless last).
// h = s_h*q1 + (s_h/127)*q2 + r2, |r2| <= 0.5*s_h/127.
// bound: |fp32 - q| <= 0.5*s*(sum|h| + s_h*A_r/127) + slop  -- same window as R10.
__global__ __launch_bounds__(256)
void cls_int8(const uint* __restrict__ Q, const float* __restrict__ b_cls,
              float* __restrict__ ws, const float* __restrict__ h,
              const float* __restrict__ W_hh, const float* __restrict__ b_hh,
              int last) {
    const int wave = threadIdx.x >> 6;
    const int lane = threadIdx.x & 63;

    if (blockIdx.x >= NBLK) {
        if (last) return;
        const int tb = (blockIdx.x - NBLK) * 4 + wave;     // [0,1280)
        const float4* h4 = (const float4*)h;
        float4 hv[5];
        #pragma unroll
        for (int k = 0; k < 5; ++k) hv[k] = h4[lane + 64*k];
        #pragma unroll
        for (int rr = 0; rr < 3; ++rr) {
            const int row = tb * 3 + rr;
            const float4* wr = (const float4*)(W_hh + (size_t)row * H);
            float s = 0.f;
            #pragma unroll
            for (int k = 0; k < 5; ++k) {
                float4 w = wr[lane + 64*k];
                s += w.x*hv[k].x + w.y*hv[k].y + w.z*hv[k].z + w.w*hv[k].w;
            }
            #pragma unroll
            for (int off = 32; off; off >>= 1) s += __shfl_down(s, off);
            if (lane == 0) ws[WS_GH + row] = s + b_hh[row];
        }
        return;
    }

    __shared__ uint qh1_s[320], qh2_s[320];
    const int tid = threadIdx.x;

    float hmax = 0.f;
    #pragma unroll
    for (int i = 0; i < 8; ++i)
        hmax = fmaxf(hmax, __uint_as_float(((const uint*)ws)[WS_HMAX8 + i * 16]));
    float sumabs = 0.f;
    #pragma unroll
    for (int i = 0; i < 8; ++i) sumabs += ws[WS_SUM8 + i * 16];
    const float s_h   = (hmax > 0.f) ? hmax / 127.0f : 0.f;
    const float invsh = (hmax > 0.f) ? 127.0f / hmax : 0.f;
    const float inv2  = invsh * 127.0f;   // 127 / s_h

    // two-level quantize h -> LDS: q1 = rn(h/s_h), q2 = rn((h - s_h*q1)*127/s_h)
    for (int i = tid; i < 320; i += 256) {
        float4 hv4 = ((const float4*)h)[i];
        int a0 = max(-127, min(127, __float2int_rn(hv4.x * invsh)));
        int a1 = max(-127, min(127, __float2int_rn(hv4.y * invsh)));
        int a2 = max(-127, min(127, __float2int_rn(hv4.z * invsh)));
        int a3 = max(-127, min(127, __float2int_rn(hv4.w * invsh)));
        int c0 = max(-127, min(127, __float2int_rn((hv4.x - s_h * (float)a0) * inv2)));
        int c1 = max(-127, min(127, __float2int_rn((hv4.y - s_h * (float)a1) * inv2)));
        int c2 = max(-127, min(127, __float2int_rn((hv4.z - s_h * (float)a2) * inv2)));
        int c3 = max(-127, min(127, __float2int_rn((hv4.w - s_h * (float)a3) * inv2)));
        qh1_s[i] = (uint)(a0 & 0xff) | ((uint)(a1 & 0xff) << 8) |
                   ((uint)(a2 & 0xff) << 16) | ((uint)(a3 & 0xff) << 24);
        qh2_s[i] = (uint)(c0 & 0xff) | ((uint)(c1 & 0xff) << 8) |
                   ((uint)(c2 & 0xff) << 16) | ((uint)(c3 & 0xff) << 24);
    }
    __syncthreads();

    uint qh1_r[5], qh2_r[5];
    #pragma unroll
    for (int k = 0; k < 5; ++k) { qh1_r[k] = qh1_s[lane + 64*k]; qh2_r[k] = qh2_s[lane + 64*k]; }

    const int row0 = blockIdx.x * 64 + wave * 16;
    float wlo = -INFINITY, whi = -INFINITY;

    for (int rr = 0; rr < 16; ++rr) {
        const int row = row0 + rr;
        if (row >= V) break;                  // wave-uniform
        const uint* __restrict__ qr = Q + (size_t)row * (H/4);
        int acc1 = 0, acc2 = 0;
        #pragma unroll
        for (int k = 0; k < 5; ++k) {
            uint u = qr[lane + 64*k];
            acc1 = dot4i8(u, qh1_r[k], acc1);
            acc2 = dot4i8(u, qh2_r[k], acc2);
        }
        float v = (float)acc1 + (float)acc2 * INV127;
        #pragma unroll
        for (int off = 32; off; off >>= 1) v += __shfl_down(v, off);
        if (lane == 0) {
            float s = ws[WS_SROW + row];
            float q = s * s_h * v + b_cls[row];
            ws[WS_LOGITS + row] = q;
            float e = 0.501f * s * (sumabs + s_h * ws[WS_ASUM + row] * INV127) + 0.002f;
            wlo = fmaxf(wlo, q - e);
            whi = fmaxf(whi, q + e);
        }
    }
    __shared__ float slo[4], shi[4];
    if (lane == 0) { slo[wave] = wlo; shi[wave] = whi; }
    __syncthreads();
    if (tid == 0) {
        ws[WS_PLO + blockIdx.x] = fmaxf(fmaxf(slo[0], slo[1]), fmaxf(slo[2], slo[3]));
        ws[WS_PHI + blockIdx.x] = fmaxf(fmaxf(shi[0], shi[1]), fmaxf(shi[2], shi[3]));
    }
}

// Single block: m = max(PLO); candidate collect; exact fp32 rescore; argmax
// (min-index ties); token/done/emb; reset per-step slots.
__global__ __launch_bounds__(1024)
void finalize(float* __restrict__ ws, const float* __restrict__ W_cls,
              const float* __restrict__ b_cls, const float* __restrict__ vocab,
              float* __restrict__ tok_out, int t, const float* __restrict__ h) {
    __shared__ float red[1024];
    __shared__ int   npass, cnt;
    __shared__ int   pblk[PBLK_CAP];
    __shared__ int   cidx[CAND_CAP];
    __shared__ float cval[CAND_CAP];
    __shared__ int   s_pred, s_done_new;
    const int tid = threadIdx.x;

    float hmax = 0.f;
    #pragma unroll
    for (int i = 0; i < 8; ++i)
        hmax = fmaxf(hmax, __uint_as_float(((const uint*)ws)[WS_HMAX8 + i * 16]));
    float sumabs = 0.f;
    #pragma unroll
    for (int i = 0; i < 8; ++i) sumabs += ws[WS_SUM8 + i * 16];
    const float s_h = (hmax > 0.f) ? hmax / 127.0f : 0.f;

    float m = -INFINITY;
    for (int b = tid; b < NBLK; b += 1024) m = fmaxf(m, ws[WS_PLO + b]);
    red[tid] = m;
    __syncthreads();
    for (int s = 512; s; s >>= 1) {
        if (tid < s) red[tid] = fmaxf(red[tid], red[tid + s]);
        __syncthreads();
    }
    m = red[0];
    if (tid == 0) { npass = 0; cnt = 0; }
    __syncthreads();

    for (int b = tid; b < NBLK; b += 1024) {
        if (ws[WS_PHI + b] >= m) {
            int p = atomicAdd(&npass, 1);
            if (p < PBLK_CAP) pblk[p] = b;
        }
    }
    __syncthreads();
    const int np = min(npass, PBLK_CAP);

    for (int k = tid; k < np * 64; k += 1024) {
        int row = pblk[k >> 6] * 64 + (k & 63);
        if (row < V) {
            float s = ws[WS_SROW + row];
            float e = 0.501f * s * (sumabs + s_h * ws[WS_ASUM + row] * INV127) + 0.002f;
            if (ws[WS_LOGITS + row] + e >= m) {
                int p = atomicAdd(&cnt, 1);
                if (p < CAND_CAP) cidx[p] = row;
            }
        }
    }
    __syncthreads();
    const int nc = min(cnt, CAND_CAP);

    const int wave = tid >> 6;
    const int lane = tid & 63;
    const float4* __restrict__ h4 = (const float4*)h;
    for (int c = wave; c < nc; c += 16) {
        int row = cidx[c];
        const float4* __restrict__ wr = (const float4*)(W_cls + (size_t)row * H);
        float s = 0.f;
        #pragma unroll
        for (int k = 0; k < 5; ++k) {
            float4 wv = wr[lane + 64*k], hvv = h4[lane + 64*k];
            s += wv.x*hvv.x + wv.y*hvv.y + wv.z*hvv.z + wv.w*hvv.w;
        }
        #pragma unroll
        for (int off = 32; off; off >>= 1) s += __shfl_down(s, off);
        if (lane == 0) cval[c] = s + b_cls[row];
    }
    __syncthreads();

    if (tid == 0) {
        float bv = -INFINITY; int bi = INT_MAX;
        for (int c = 0; c < nc; ++c) {
            float v = cval[c]; int i = cidx[c];
            if (v > bv || (v == bv && i < bi)) { bv = v; bi = i; }
        }
        int done = ((const int*)ws)[WS_DONE];
        int pred = bi;
        tok_out[t] = (float)(done ? 0 : pred);
        int dn = done | (pred == 0);
        ((int*)ws)[WS_DONE] = dn;
        s_pred = pred; s_done_new = dn;
    }
    __syncthreads();
    if (!s_done_new && tid < E)
        ws[WS_EMB + tid] = vocab[(size_t)s_pred * E + tid];
    if (tid < 8) { ws[WS_SUM8 + tid * 16] = 0.f; ((uint*)ws)[WS_HMAX8 + tid * 16] = 0u; }
}

// ---------- fp32 fallback path (tiny-ws only, R0-proven) ----------
__global__ __launch_bounds__(256)
void fb_gru_matvec(const float* __restrict__ W_ih, const float* __restrict__ W_hh,
                   const float* __restrict__ b_ih, const float* __restrict__ b_hh,
                   float* __restrict__ ws) {
    const int wave = threadIdx.x >> 6;
    const int lane = threadIdx.x & 63;
    const int row = blockIdx.x * 4 + wave;
    const float4* __restrict__ emb4 = (const float4*)(ws + WS_EMB);
    const float4* __restrict__ h4   = (const float4*)(ws + WS_H0);
    const float4* __restrict__ wi = (const float4*)(W_ih + (size_t)row * E);
    float s1 = 0.f;
    for (int i = lane; i < 75; i += 64) {
        float4 w = wi[i], e = emb4[i];
        s1 += w.x*e.x + w.y*e.y + w.z*e.z + w.w*e.w;
    }
    const float4* __restrict__ wh = (const float4*)(W_hh + (size_t)row * H);
    float s2 = 0.f;
    #pragma unroll
    for (int k = 0; k < 5; ++k) {
        float4 w = wh[lane + 64*k], hv = h4[lane + 64*k];
        s2 += w.x*hv.x + w.y*hv.y + w.z*hv.z + w.w*hv.w;
    }
    #pragma unroll
    for (int off = 32; off; off >>= 1) {
        s1 += __shfl_down(s1, off);
        s2 += __shfl_down(s2, off);
    }
    if (lane == 0) {
        ws[FB_GI + row] = s1 + b_ih[row];
        ws[FB_GH + row] = s2 + b_hh[row];
    }
}

__global__ __launch_bounds__(256)
void fb_gru_combine(float* __restrict__ ws, float* __restrict__ hid_out) {
    int j = blockIdx.x * 256 + threadIdx.x;
    if (j >= H) return;
    int done = ((const int*)ws)[WS_DONE];
    float gir = ws[FB_GI + j], giz = ws[FB_GI + H + j], gin = ws[FB_GI + 2*H + j];
    float ghr = ws[FB_GH + j], ghz = ws[FB_GH + H + j], ghn = ws[FB_GH + 2*H + j];
    float r = 1.f / (1.f + expf(-(gir + ghr)));
    float z = 1.f / (1.f + expf(-(giz + ghz)));
    float n = tanhf(gin + r * ghn);
    float hold = ws[WS_H0 + j];
    float hnew = done ? hold : (1.f - z) * n + z * hold;
    ws[WS_H0 + j] = hnew;
    hid_out[j] = hnew;
}

__global__ __launch_bounds__(256)
void fb_logits_argmax(const float* __restrict__ W_cls, const float* __restrict__ b_cls,
                      float* __restrict__ ws) {
    const int wave = threadIdx.x >> 6;
    const int lane = threadIdx.x & 63;
    const int row0 = blockIdx.x * 16 + wave * 4;
    const float4* __restrict__ h4 = (const float4*)(ws + WS_H0);
    float best = -INFINITY;
    int bidx = INT_MAX;
    for (int rr = 0; rr < 4; ++rr) {
        const int row = row0 + rr;
        const float4* __restrict__ wr = (const float4*)(W_cls + (size_t)row * H);
        float s = 0.f;
        #pragma unroll
        for (int k = 0; k < 5; ++k) {
            float4 w = wr[lane + 64*k], hv = h4[lane + 64*k];
            s += w.x*hv.x + w.y*hv.y + w.z*hv.z + w.w*hv.w;
        }
        #pragma unroll
        for (int off = 32; off; off >>= 1) s += __shfl_down(s, off);
        if (lane == 0) {
            float logit = s + b_cls[row];
            if (logit > best) { best = logit; bidx = row; }
        }
    }
    __shared__ float sval[4];
    __shared__ int   sidx[4];
    if (lane == 0) { sval[wave] = best; sidx[wave] = bidx; }
    __syncthreads();
    if (threadIdx.x == 0) {
        float bv = sval[0]; int bi = sidx[0];
        #pragma unroll
        for (int w = 1; w < 4; ++w)
            if (sval[w] > bv || (sval[w] == bv && sidx[w] < bi)) { bv = sval[w]; bi = sidx[w]; }
        ws[FB_PVAL + blockIdx.x] = bv;
        ((int*)ws)[FB_PIDX + blockIdx.x] = bi;
    }
}

__global__ __launch_bounds__(1024)
void fb_argmax_update(float* __restrict__ ws, const float* __restrict__ vocab,
                      float* __restrict__ tok_out, int t) {
    __shared__ float sval[1024];
    __shared__ int   sidx[1024];
    const int tid = threadIdx.x;
    float best = -INFINITY;
    int bidx = INT_MAX;
    for (int i = tid; i < FB_NPART; i += 1024) {
        float v = ws[FB_PVAL + i];
        int  id = ((const int*)ws)[FB_PIDX + i];
        if (v > best || (v == best && id < bidx)) { best = v; bidx = id; }
    }
    sval[tid] = best; sidx[tid] = bidx;
    __syncthreads();
    #pragma unroll
    for (int s = 512; s; s >>= 1) {
        if (tid < s) {
            if (sval[tid+s] > sval[tid] ||
                (sval[tid+s] == sval[tid] && sidx[tid+s] < sidx[tid])) {
                sval[tid] = sval[tid+s]; sidx[tid] = sidx[tid+s];
            }
        }
        __syncthreads();
    }
    __shared__ int s_pred, s_donenew;
    if (tid == 0) {
        int pred = sidx[0];
        int done = ((const int*)ws)[WS_DONE];
        tok_out[t] = (float)(done ? 0 : pred);
        int done_new = done | (pred == 0);
        ((int*)ws)[WS_DONE] = done_new;
        s_pred = pred; s_donenew = done_new;
    }
    __syncthreads();
    if (!s_donenew && tid < E)
        ws[WS_EMB + tid] = vocab[(size_t)s_pred * E + tid];
}

extern "C" void kernel_launch(void* const* d_in, const int* in_sizes, int n_in,
                              void* d_out, int out_size, void* d_ws, size_t ws_size,
                              hipStream_t stream) {
    const float* hidden0   = (const float*)d_in[0];
    const float* start_emb = (const float*)d_in[1];
    const float* W_ih      = (const float*)d_in[2];
    const float* W_hh      = (const float*)d_in[3];
    const float* b_ih      = (const float*)d_in[4];
    const float* b_hh      = (const float*)d_in[5];
    const float* W_cls     = (const float*)d_in[6];
    const float* b_cls     = (const float*)d_in[7];
    const float* vocab     = (const float*)d_in[8];
    float* out = (float*)d_out;
    float* ws  = (float*)d_ws;

    hipLaunchKernelGGL(init_state, dim3(5), dim3(256), 0, stream, hidden0, start_emb, ws);

    if (ws_size >= WS_BYTES_NEEDED) {
        uint* Q = (uint*)((char*)d_ws + WS_Q_BYTEOFF);
        hipLaunchKernelGGL(convert_int8, dim3(V/4 + GHBLK), dim3(256), 0, stream,
                           W_cls, Q, ws, W_hh, b_hh);
        for (int k = 0; k < L; ++k) {
            const float* hin = ws + ((k & 1) ? WS_H1 : WS_H0);
            float* hout      = ws + ((k & 1) ? WS_H0 : WS_H1);
            hipLaunchKernelGGL(gru_fused, dim3(H), dim3(192), 0, stream,
                               W_ih, b_ih, ws, hin, hout, out + L + (size_t)k * H);
            hipLaunchKernelGGL(cls_int8, dim3(NBLK + GHBLK), dim3(256), 0, stream,
                               Q, b_cls, ws, hout, W_hh, b_hh, (k == L - 1) ? 1 : 0);
            hipLaunchKernelGGL(finalize, dim3(1), dim3(1024), 0, stream,
                               ws, W_cls, b_cls, vocab, out, k, hout);
        }
    } else {
        for (int t = 0; t < L; ++t) {
            hipLaunchKernelGGL(fb_gru_matvec, dim3(960), dim3(256), 0, stream,
                               W_ih, W_hh, b_ih, b_hh, ws);
            hipLaunchKernelGGL(fb_gru_combine, dim3(5), dim3(256), 0, stream,
                               ws, out + L + (size_t)t * H);
            hipLaunchKernelGGL(fb_logits_argmax, dim3(FB_NPART), dim3(256), 0, stream,
                               W_cls, b_cls, ws);
            hipLaunchKernelGGL(fb_argmax_update, dim3(1), dim3(1024), 0, stream,
                               ws, vocab, out, t);
        }
    }
}